// Round 6
// baseline (382.879 us; speedup 1.0000x reference)
//
#include <hip/hip_runtime.h>

// Problem constants
#define NB 64
#define NP 500
#define NC 128
#define NH 256
#define EPS_BN 1e-5f

// Block-local edge list cap (expected ~600 i<j edges/batch; 6.8x margin;
// R1-R5 passed exact-match with per-band caps implying true counts are small)
#define ECAP 4096

// ws word layout: just the activation matrices, feature-major [256][64]
#define CT_OFF 0
#define H1_OFF (NH * NB)
#define H2_OFF (2 * NH * NB)

// Output layout: tc[64] | tsys[64] | l2_points[4096000] | correlation[8192]
#define OUT_PTS_OFF 128
#define OUT_CORR_OFF 4096128

// R3-R5 lesson (journal): in-kernel spin barriers cost ~25-30us each on
// gfx950 regardless of fence strength (seq_cst==rel/acq), topology
// (flat/hierarchical/per-batch), or occupancy (1 vs 4 waves/SIMD). Structural
// to spin-wait visibility, not protocol. Therefore: ZERO cross-block sync.
// Scan is recomputed per corr block (cheap); layer deps use kernel boundaries.

#define CHK(P, I, Q, J)                                     \
  if ((I) < (J)) {                                          \
    float dot_ = P.x * Q.x + P.y * Q.y + P.z * Q.z;         \
    float d_ = sqrtf(fabsf(P.w + Q.w - 2.f * dot_));        \
    if (d_ > 0.19f && d_ < 0.21f) {                         \
      int e_ = atomicAdd(&lcnt, 1);                         \
      if (e_ < ECAP) sm.c.eL[e_] = ((I) << 16) | (J);       \
    }                                                       \
  }

// ---------------------------------------------------------------------------
// K1: even blocks <1024: corr (own scan, block-local edges); odd: copy;
//     blocks 1024..1087: per-batch misc. No inter-block dependencies.
// ---------------------------------------------------------------------------
__global__ __launch_bounds__(256) void k1(
    const float* __restrict__ xyz,    // [B,3,N]
    const float* __restrict__ data,   // [B,C,N] l2_points
    const float* __restrict__ l3,     // [B,C]
    const float* __restrict__ temp,   // [B,1,N]
    const float* __restrict__ b4,     // [1]
    float* __restrict__ out,
    float* __restrict__ ws) {
  const int blk = blockIdx.x;
  const int tid = threadIdx.x;

  __shared__ union {
    struct {
      float4 pt[NP];        // 8000 B: x,y,z,|p|^2
      int eL[ECAP];         // 16384 B: block-local edge list
      float dT[16 * 504];   // 32256 B: dT[c][j], 16 channels
      float corrp[16];
    } c;
    struct { float wsum[4]; } m;
  } sm;  // ~56.7 KB -> 2 blocks/CU
  __shared__ int lcnt;

  if (blk < 1024) {
    const int role = blk & 1;
    const int id = blk >> 1;
    if (role == 1) {
      // ---------------- copy: l2_points -> out (memory-bound) ------------
      const float4* src = (const float4*)data;
      float4* dst = (float4*)(out + OUT_PTS_OFF);
      for (int idx = id * 256 + tid; idx < 1024000; idx += 512 * 256)
        dst[idx] = src[idx];
      return;
    }
    // ---------------- corr: batch b, channels c0..c0+15 ------------------
    const int b = id >> 3;
    const int c0 = (id & 7) * 16;
    if (tid == 0) lcnt = 0;
    if (tid < 16) sm.c.corrp[tid] = 0.f;

    // stage points (+|p|^2, matching ref's s_i + s_j - 2 dot ordering)
    const float* xr = xyz + b * 1500;
    for (int idx = tid; idx < NP; idx += 256) {
      float x = xr[idx], y = xr[500 + idx], z = xr[1000 + idx];
      sm.c.pt[idx] = make_float4(x, y, z, x * x + y * y + z * z);
    }
    // stage 16 channels, transposed: dT[c][j], contiguous b128 writes
    const float4* in4 = (const float4*)data + b * 16000 + c0 * 125;
    for (int k = tid; k < 2000; k += 256) {
      float4 v = in4[k];
      int c = k / 125;
      int j4 = k - c * 125;
      *(float4*)(&sm.c.dT[c * 504 + 4 * j4]) = v;
    }
    __syncthreads();

    // full pair scan (strictly upper i<j); ~1.5 MFLOP, block-local
    {
      const int i0 = tid, i1 = tid + 256;
      float4 p0 = sm.c.pt[i0];
      float4 p1 = (i1 < NP) ? sm.c.pt[i1] : make_float4(0.f, 0.f, 0.f, 0.f);
#pragma unroll 4
      for (int j = 1; j < NP; ++j) {
        float4 q = sm.c.pt[j];  // wave-uniform -> LDS broadcast
        CHK(p0, i0, q, j)
        CHK(p1, i1, q, j)
      }
    }
    __syncthreads();

    // gather: quad = 4-channel group, 64 edge slots per wave
    const int E = lcnt < ECAP ? lcnt : ECAP;
    const int quad = tid & 3;
    const int slot = tid >> 2;
    float a0 = 0.f, a1 = 0.f, a2 = 0.f, a3 = 0.f;
    const float* Cb = sm.c.dT + quad * 4 * 504;
    for (int e = slot; e < E; e += 64) {
      int ij = sm.c.eL[e];
      int i = ij >> 16, j = ij & 0xffff;
      a0 += Cb[i] * Cb[j];
      a1 += Cb[504 + i] * Cb[504 + j];
      a2 += Cb[1008 + i] * Cb[1008 + j];
      a3 += Cb[1512 + i] * Cb[1512 + j];
    }
    for (int off = 4; off < 64; off <<= 1) {  // preserve quad
      a0 += __shfl_xor(a0, off);
      a1 += __shfl_xor(a1, off);
      a2 += __shfl_xor(a2, off);
      a3 += __shfl_xor(a3, off);
    }
    if ((tid & 63) < 4) {  // one representative per quad per wave
      atomicAdd(&sm.c.corrp[quad * 4 + 0], a0);
      atomicAdd(&sm.c.corrp[quad * 4 + 1], a1);
      atomicAdd(&sm.c.corrp[quad * 4 + 2], a2);
      atomicAdd(&sm.c.corrp[quad * 4 + 3], a3);
    }
    __syncthreads();
    if (tid < 16) {
      // mask symmetric: ordered count = 2*lcnt, ordered sum = 2*upper sum
      float denom = fmaxf(2.f * (float)lcnt, 1.f);
      float v = 2.f * sm.c.corrp[tid] / denom;
      out[OUT_CORR_OFF + b * NC + c0 + tid] = v;
      ws[CT_OFF + (c0 + tid) * 64 + b] = v;
    }
  } else {
    // ---------------- misc for batch b: tsys, cT sa4 rows, tc bias -------
    const int b = blk - 1024;
    float s = 0.f;
    for (int i = tid; i < NP; i += 256) s += temp[b * NP + i];
    for (int off = 32; off; off >>= 1) s += __shfl_xor(s, off);
    if ((tid & 63) == 0) sm.m.wsum[tid >> 6] = s;
    __syncthreads();
    if (tid == 0)
      out[64 + b] = (sm.m.wsum[0] + sm.m.wsum[1] + sm.m.wsum[2] +
                     sm.m.wsum[3]) * (1.f / 500.f);
    if (tid < 128) ws[CT_OFF + (128 + tid) * 64 + b] = l3[b * NC + tid];
    if (tid == 0) out[b] = b4[0];  // tc = bias; final layer atomicAdds
  }
}

// ---------------------------------------------------------------------------
// Layer: y = relu(BN(x @ W^T + bias)); BN over batch dim (64 = one wave).
// 256 blocks (one output feature) x 256 threads (4 waves split K).
// If w4 != null: atomicAdd w4[o]*h into tc[b] instead of storing.
// (R1-proven implementation.)
// ---------------------------------------------------------------------------
__global__ __launch_bounds__(256) void layer_k(
    const float* __restrict__ xT, const float* __restrict__ W,
    const float* __restrict__ bias, const float* __restrict__ g,
    const float* __restrict__ be, float* __restrict__ yT,
    const float* __restrict__ w4, float* __restrict__ tc) {
  const int o = blockIdx.x;
  const int b = threadIdx.x & 63;
  const int w = threadIdx.x >> 6;
  const float* wr = W + o * NH + w * 64;
  const float* xp = xT + (w * 64) * 64 + b;
  float acc = 0.f;
#pragma unroll
  for (int i = 0; i < 64; ++i) acc += xp[i * 64] * wr[i];
  __shared__ float part[4][64];
  part[w][b] = acc;
  __syncthreads();
  if (w == 0) {
    float t = part[0][b] + part[1][b] + part[2][b] + part[3][b] + bias[o];
    float s1 = t;
    for (int off = 32; off; off >>= 1) s1 += __shfl_xor(s1, off);
    float m = s1 * (1.f / 64.f);
    float d = t - m;
    float s2 = d * d;
    for (int off = 32; off; off >>= 1) s2 += __shfl_xor(s2, off);
    float var = s2 * (1.f / 64.f);
    float h = g[o] * d * rsqrtf(var + EPS_BN) + be[o];
    h = fmaxf(h, 0.f);
    if (w4) {
      atomicAdd(&tc[b], w4[o] * h);
    } else {
      yT[o * 64 + b] = h;
    }
  }
}

extern "C" void kernel_launch(void* const* d_in, const int* in_sizes, int n_in,
                              void* d_out, int out_size, void* d_ws,
                              size_t ws_size, hipStream_t stream) {
  const float* xyz = (const float*)d_in[0];
  const float* pts = (const float*)d_in[1];
  const float* l3 = (const float*)d_in[2];
  const float* temp = (const float*)d_in[3];
  const float* w0 = (const float*)d_in[4];
  const float* b0 = (const float*)d_in[5];
  const float* g0 = (const float*)d_in[6];
  const float* be0 = (const float*)d_in[7];
  const float* w1 = (const float*)d_in[8];
  const float* b1 = (const float*)d_in[9];
  const float* g1 = (const float*)d_in[10];
  const float* be1 = (const float*)d_in[11];
  const float* w2 = (const float*)d_in[12];
  const float* b2 = (const float*)d_in[13];
  const float* g2 = (const float*)d_in[14];
  const float* be2 = (const float*)d_in[15];
  const float* w3 = (const float*)d_in[16];
  const float* b3 = (const float*)d_in[17];
  const float* g3 = (const float*)d_in[18];
  const float* be3 = (const float*)d_in[19];
  const float* w4 = (const float*)d_in[20];
  const float* b4 = (const float*)d_in[21];

  float* out = (float*)d_out;
  float* ws = (float*)d_ws;
  float* cT = ws + CT_OFF;
  float* hA = ws + H1_OFF;
  float* hB = ws + H2_OFF;

  k1<<<1088, 256, 0, stream>>>(xyz, pts, l3, temp, b4, out, ws);
  layer_k<<<256, 256, 0, stream>>>(cT, w0, b0, g0, be0, hA, nullptr, nullptr);
  layer_k<<<256, 256, 0, stream>>>(hA, w1, b1, g1, be1, hB, nullptr, nullptr);
  layer_k<<<256, 256, 0, stream>>>(hB, w2, b2, g2, be2, hA, nullptr, nullptr);
  layer_k<<<256, 256, 0, stream>>>(hA, w3, b3, g3, be3, nullptr, w4, out);
}